// Round 1
// baseline (284.087 us; speedup 1.0000x reference)
//
#include <hip/hip_runtime.h>

// PoolingNms: 3 chained pool/unpool passes (k=3,5,6) on 16x1x1080x1920 fp32.
// lcm(3,5,6)=30 -> every 30x30 tile is fully independent across all stages.
//
// This version: ONE WAVE (64 threads) per 30x30 tile.
//  - __launch_bounds__(64) => __syncthreads() lowers to a wave_barrier
//    (zero-cost compiler fence; no s_barrier emitted). Per-wave LDS ops are
//    in-order, so in-place stage updates stay correct.
//  - LDS = 3.6 KiB/block => occupancy capped by waves (32/CU), not LDS.
//    Previous 30x240/256-thread version: 28.5 KiB LDS -> 20 waves/CU and
//    4 full-block barriers; counters showed 46% occupancy, 21% VALUBusy,
//    26% HBM => latency-bound. This removes both limiters.

#define IMG_H 1080
#define IMG_W 1920
#define TILE 30
#define NTHREADS 64

// One stage: KxK non-overlapping windows over the 30x30 LDS tile.
// Each window handled by exactly one lane (disjoint -> in-place safe).
// Strict '>' scan in row-major (r*K+c) order == jnp.argmax first-occurrence.
template <int K>
__device__ __forceinline__ void nms_stage(float (*tile)[TILE], int t) {
    constexpr int NW = TILE / K;  // windows per side
    for (int w = t; w < NW * NW; w += NTHREADS) {
        const int wr = w / NW;
        const int wc = w - wr * NW;
        const int r0 = wr * K;
        const int c0 = wc * K;
        float mx = -1.0f;  // inputs are >= 0
        int am = 0;
#pragma unroll
        for (int r = 0; r < K; ++r)
#pragma unroll
            for (int c = 0; c < K; ++c) {
                const float v = tile[r0 + r][c0 + c];
                if (v > mx) { mx = v; am = r * K + c; }
            }
#pragma unroll
        for (int r = 0; r < K; ++r)
#pragma unroll
            for (int c = 0; c < K; ++c)
                tile[r0 + r][c0 + c] = (r * K + c == am) ? mx : 0.0f;
    }
    __syncthreads();  // single-wave workgroup: compiles to wave_barrier only
}

__global__ __launch_bounds__(NTHREADS) void pooling_nms_kernel(
    const float* __restrict__ x, float* __restrict__ out) {
    __shared__ float tile[TILE][TILE];

    const int t = threadIdx.x;
    const int col0 = blockIdx.x * TILE;
    const int row0 = blockIdx.y * TILE;
    const size_t base = (size_t)blockIdx.z * (IMG_H * (size_t)IMG_W) +
                        (size_t)row0 * IMG_W + col0;
    const float* src = x + base;
    float* dst = out + base;

    // float2 load: 30*30/2 = 450 vec2 per block, 15 per row (120 B, 8B-aligned).
    constexpr int V2PR = TILE / 2;    // 15
    constexpr int NV = TILE * V2PR;   // 450
    for (int i = t; i < NV; i += NTHREADS) {
        const int r = i / V2PR;
        const int c2 = i - r * V2PR;
        const float2 v =
            *reinterpret_cast<const float2*>(src + (size_t)r * IMG_W + c2 * 2);
        *reinterpret_cast<float2*>(&tile[r][c2 * 2]) = v;
    }
    __syncthreads();

    nms_stage<3>(tile, t);  // 10x10 = 100 windows
    nms_stage<5>(tile, t);  //  6x6  =  36 windows
    nms_stage<6>(tile, t);  //  5x5  =  25 windows

    for (int i = t; i < NV; i += NTHREADS) {
        const int r = i / V2PR;
        const int c2 = i - r * V2PR;
        *reinterpret_cast<float2*>(dst + (size_t)r * IMG_W + c2 * 2) =
            *reinterpret_cast<const float2*>(&tile[r][c2 * 2]);
    }
}

extern "C" void kernel_launch(void* const* d_in, const int* in_sizes, int n_in,
                              void* d_out, int out_size, void* d_ws, size_t ws_size,
                              hipStream_t stream) {
    const float* x = (const float*)d_in[0];
    float* out = (float*)d_out;
    dim3 grid(IMG_W / TILE, IMG_H / TILE, 16);  // 64 x 36 x 16 = 36864 blocks
    pooling_nms_kernel<<<grid, NTHREADS, 0, stream>>>(x, out);
}

// Round 2
// 249.585 us; speedup vs baseline: 1.1382x; 1.1382x over previous
//
#include <hip/hip_runtime.h>
#include <stdint.h>

// PoolingNms: 3 chained pool/unpool passes (k=3,5,6) on 16x1x1080x1920 fp32.
// lcm(3,5,6)=30 -> every 30x30 tile independent. Alignment analysis (round 1
// post-mortem): tile width must be a multiple of lcm(30 floats, 64 B) = 240
// floats (960 B) or HBM sees partial-line writes (measured 1.2x WRITE_SIZE
// amplification + 11.6M LDS bank conflicts with 30-wide tiles).
//
// This version: 30x240 strips (round-0 geometry, 0 write-amp, ~0 conflicts)
// + in-block double-buffered pipeline to fix round-0's exposed latency:
//   - 512 persistent blocks (2/CU at 57.6 KB LDS), 9 strips each
//   - global_load_lds (16 B) prefetches strip j+1 during compute of strip j
//   - inter-stage barriers: raw `s_waitcnt lgkmcnt(0); s_barrier` -> prefetch
//     stays in flight (plain __syncthreads would drain vmcnt(0) each time)
//   - strip switch: counted `s_waitcnt vmcnt(7)` (the 7+ stores issued after
//     the prefetch loads guarantee all loads retired; stores keep flying)

#define IMG_H 1080
#define IMG_W 1920
#define TILE_H 30
#define TILE_W 240
#define NTHREADS 256
#define V4PR (TILE_W / 4)            // 60 vec4 per row
#define NV4 (TILE_H * V4PR)          // 1800 vec4 per strip

#define NSX (IMG_W / TILE_W)         // 8
#define NSY (IMG_H / TILE_H)         // 36
#define NB 16
#define NSTRIPS (NSX * NSY * NB)     // 4608
#define NBLOCKS 512
#define SPB (NSTRIPS / NBLOCKS)      // 9 strips per block

#define GPTR(p) ((const __attribute__((address_space(1))) void*)(p))
#define LPTR(p) ((__attribute__((address_space(3))) void*)(p))

// One stage: KxK non-overlapping windows, each owned by exactly one thread
// (disjoint -> in-place safe). Strict '>' scan in row-major (r*K+c) order
// == jnp.argmax first-occurrence. (Ties only possible at max==0, where the
// output is all-zeros regardless of argmax choice.)
template <int K>
__device__ __forceinline__ void nms_stage(float (*tile)[TILE_W], int t) {
    constexpr int NWR = TILE_H / K;
    constexpr int NWC = TILE_W / K;
    for (int w = t; w < NWR * NWC; w += NTHREADS) {
        const int wr = w / NWC;
        const int wc = w - wr * NWC;
        const int r0 = wr * K;
        const int c0 = wc * K;
        float mx = -1.0f;  // inputs are >= 0
        int am = 0;
#pragma unroll
        for (int r = 0; r < K; ++r)
#pragma unroll
            for (int c = 0; c < K; ++c) {
                const float v = tile[r0 + r][c0 + c];
                if (v > mx) { mx = v; am = r * K + c; }
            }
#pragma unroll
        for (int r = 0; r < K; ++r)
#pragma unroll
            for (int c = 0; c < K; ++c)
                tile[r0 + r][c0 + c] = (r * K + c == am) ? mx : 0.0f;
    }
}

__global__ __launch_bounds__(NTHREADS) void pooling_nms_kernel(
    const float* __restrict__ x, float* __restrict__ out) {
    __shared__ float tile[2][TILE_H][TILE_W];  // 57.6 KB -> 2 blocks/CU

    const int t = threadIdx.x;
    const int s0 = blockIdx.x * SPB;

    // Per-thread (row, vec4-col) for the staging loops; advance by +256 vec4
    // per iteration without divisions (256 = 4*60 + 16).
    const int r_t = t / V4PR;
    const int c4_t = t - r_t * V4PR;

    auto strip_base = [&](int s) -> size_t {
        const int xs = s % NSX;
        const int rem = s / NSX;
        const int ys = rem % NSY;
        const int z = rem / NSY;
        return (size_t)z * (IMG_H * (size_t)IMG_W) +
               (size_t)(ys * TILE_H) * IMG_W + (size_t)xs * TILE_W;
    };

    // Async global -> LDS staging of one 30x240 strip (16 B granules).
    // LDS dest is linear in vec4 index v == wave-uniform base + lane*16: ok.
    auto prefetch = [&](int s, int buf) {
        const float* src = x + strip_base(s);
        int r = r_t, c4 = c4_t;
        for (int v = t; v < NV4; v += NTHREADS) {
            __builtin_amdgcn_global_load_lds(
                GPTR(src + (size_t)r * IMG_W + c4 * 4),
                LPTR((char*)&tile[buf][0][0] + (size_t)v * 16), 16, 0, 0);
            r += 4; c4 += 16;
            if (c4 >= V4PR) { c4 -= V4PR; r += 1; }
        }
    };

    auto store_strip = [&](int s, int buf) {
        float* dst = out + strip_base(s);
        int r = r_t, c4 = c4_t;
        for (int v = t; v < NV4; v += NTHREADS) {
            *reinterpret_cast<float4*>(dst + (size_t)r * IMG_W + c4 * 4) =
                *reinterpret_cast<const float4*>(&tile[buf][r][c4 * 4]);
            r += 4; c4 += 16;
            if (c4 >= V4PR) { c4 -= V4PR; r += 1; }
        }
    };

    prefetch(s0, 0);
    asm volatile("s_waitcnt vmcnt(0)\n\ts_barrier" ::: "memory");

    for (int i = 0; i < SPB; ++i) {
        const int buf = i & 1;
        if (i + 1 < SPB) prefetch(s0 + i + 1, buf ^ 1);  // stays in flight

        nms_stage<3>(tile[buf], t);  // 10x80 = 800 windows
        asm volatile("s_waitcnt lgkmcnt(0)\n\ts_barrier" ::: "memory");
        nms_stage<5>(tile[buf], t);  //  6x48 = 288 windows
        asm volatile("s_waitcnt lgkmcnt(0)\n\ts_barrier" ::: "memory");
        nms_stage<6>(tile[buf], t);  //  5x40 = 200 windows
        asm volatile("s_waitcnt lgkmcnt(0)\n\ts_barrier" ::: "memory");

        store_strip(s0 + i, buf);
        // Counted wait: >=7 stores were issued after the <=8 prefetch loads,
        // so vmcnt(7) proves all prefetch loads landed; stores keep flying.
        asm volatile("s_waitcnt vmcnt(7) lgkmcnt(0)\n\ts_barrier" ::: "memory");
    }
}

extern "C" void kernel_launch(void* const* d_in, const int* in_sizes, int n_in,
                              void* d_out, int out_size, void* d_ws, size_t ws_size,
                              hipStream_t stream) {
    const float* x = (const float*)d_in[0];
    float* out = (float*)d_out;
    pooling_nms_kernel<<<dim3(NBLOCKS), NTHREADS, 0, stream>>>(x, out);
}